// Round 10
// baseline (242.867 us; speedup 1.0000x reference)
//
#include <hip/hip_runtime.h>

#define BSHIFT 7            // bucket = dst >> 7 (128 nodes/bucket)
#define MAXB   1024         // max buckets supported by hist arrays
#define BPAD   16           // bcnt line padding: one counter per 64 B line
#define BCAP   3456         // padded edges/bucket (mean ~3.0k incl pad-to-16, ~+8 sigma)
#define CHUNK  4096         // edges per k_bin block (16 KB LDS stage, 1024 thr)

typedef __bf16 bf16x8 __attribute__((ext_vector_type(8)));
typedef float  f32x4  __attribute__((ext_vector_type(4)));
typedef float  f32x2  __attribute__((ext_vector_type(2)));

__device__ __forceinline__ unsigned short f2b(float f) {  // fp32 -> bf16 RNE
  unsigned u = __float_as_uint(f);
  return (unsigned short)((u + 0x7fffu + ((u >> 16) & 1u)) >> 16);
}
__device__ __forceinline__ float b2f_lo(unsigned u) {  // low bf16 of packed pair
  return __uint_as_float(u << 16);
}
__device__ __forceinline__ float b2f_hi(unsigned u) {
  return __uint_as_float(u & 0xffff0000u);
}

// ---------------------------------------------------------------- bin (+fold)
// [0,nbin): bin edges into buckets (packed uint: dloc<<17|src, dloc 7 bits).
// CHUNK=4096 -> 391 bin blocks (round-9: 196 blocks = 0.77/CU, a quarter of
// the machine idle; bcnt line-padding already removed the global-atomic
// serialization that motivated CHUNK=8192). LDS 28 KB.
// [nbin,nbin+145): castW / layer-2 fold / zero rows, gated to t<256.
__global__ __launch_bounds__(1024) void k_bin(
    const int* __restrict__ ei, int E, int* __restrict__ bcnt,
    unsigned* __restrict__ edg,
    const float* __restrict__ W1l, const float* __restrict__ W1r,
    unsigned short* __restrict__ Wb,
    const float* __restrict__ Wc, const float* __restrict__ bc,
    const float* __restrict__ W2l, const float* __restrict__ W2r,
    const float* __restrict__ b2, unsigned short* __restrict__ Mb,
    float* __restrict__ bias2,
    unsigned short* __restrict__ xb, unsigned* __restrict__ xq,
    unsigned short* __restrict__ Pnb, int ZR, int nbin) {
  __shared__ int lh[MAXB], lbase[MAXB], lcur[MAXB];   // 12 KB
  __shared__ int ldst[CHUNK];                         // 16 KB dst stage
  const int b = blockIdx.x;
  const int t = threadIdx.x;
  if (b < nbin) {
    for (int i = t; i < MAXB; i += 1024) { lh[i] = 0; lcur[i] = 0; }
    __syncthreads();
    const int e0 = b * CHUNK;
    const int n = min(E - e0, CHUNK);
    const int* __restrict__ src = ei;
    const int* __restrict__ dst = ei + E;
    for (int j = t; j < n; j += 1024) {
      int d = dst[e0 + j];
      ldst[j] = d;
      atomicAdd(&lh[((unsigned)d) >> BSHIFT], 1);
    }
    __syncthreads();
    for (int i = t; i < MAXB; i += 1024)
      if (lh[i]) lbase[i] = atomicAdd(&bcnt[i * BPAD], lh[i]);
    __syncthreads();
    for (int j = t; j < n; j += 1024) {
      int d = ldst[j];
      unsigned s = (unsigned)src[e0 + j];
      int bk = ((unsigned)d) >> BSHIFT;
      int p = lbase[bk] + atomicAdd(&lcur[bk], 1);
      if (p < BCAP) edg[(size_t)bk * BCAP + p] = ((unsigned)(d & 127) << 17) | s;
    }
  } else if (t < 256) {
    int bb = b - nbin;
    if (bb < 128) {
      int idx = bb * 256 + t;
      int col = idx >> 8, k = idx & 255;
      float v = (k < 128) ? W1l[col * 128 + k] : W1r[col * 128 + (k - 128)];
      Wb[col * 256 + k] = f2b(v);
    } else if (bb < 144) {
      int mb = bb - 128;
      int mat = mb >> 3;
      const float* W2 = mat ? W2r : W2l;
      int o = (mb & 7) * 2 + (t >> 7);
      int k = t & 127;
      float s = 0.f;
      for (int j = 0; j < 128; ++j) s = fmaf(Wc[o * 128 + j], W2[j * 128 + k], s);
      Mb[(size_t)(mat * 16 + o) * 128 + k] = f2b(s);
      if (mb == 0 && t < 16) {
        float sb = bc[t];
        for (int j = 0; j < 128; ++j) sb = fmaf(Wc[t * 128 + j], b2[j], sb);
        bias2[t] = sb;
      }
    } else {
      if (t < 64) ((unsigned*)(xb + (size_t)ZR * 128))[t] = 0;   // zero row (bf16)
      if (t < 32) xq[(size_t)ZR * 32 + t] = 0;                   // zero row (fp8)
      if (t < 8)  ((unsigned*)(Pnb + (size_t)ZR * 16))[t] = 0;   // zero row (bf16)
    }
  }
}

// ---------------------------------------------------------------- build ∥ cast
// [0,nbuck): per-bucket CSR finalize (degree hist + pad-to-16 scan + src
// scatter in LDS, coalesced int4 writes). BSHIFT=7 -> 782 blocks (round-9:
// 391 blocks filled only 76% of the 2-block/CU wave-cap slots in one
// full-latency round; 782 half-size blocks -> ~1.5 shorter rounds and
// halved per-bucket LDS atomic contention). ~16 KB LDS.
// [nbuck,...): streaming cast x -> bf16 xb + fp8 xq (independent of build,
// fills the CUs build leaves idle; graph capture forbids multi-stream).
__global__ __launch_bounds__(1024) void k_buildcast(
    const unsigned* __restrict__ edg, const int* __restrict__ bcnt,
    int* __restrict__ eidx, int* __restrict__ rowcnt, int N, int ZR,
    int nbuck, const float* __restrict__ x, unsigned short* __restrict__ xb,
    unsigned* __restrict__ xq, int ngroups) {
  __shared__ int lsrc[BCAP];                       // 13.5 KB
  __shared__ int lcnt[128], lstart[128], lcur[128];
  __shared__ int wsum[2];
  const int b = blockIdx.x;
  const int t = threadIdx.x;
  if (b >= nbuck) {                                // ---- cast block
    int g = (b - nbuck) * 1024 + t;
    if (g < ngroups) {
      float4 v = ((const float4*)x)[g];
      ushort4 o;
      o.x = f2b(v.x); o.y = f2b(v.y); o.z = f2b(v.z); o.w = f2b(v.w);
      ((ushort4*)xb)[g] = o;
      int q8 = __builtin_amdgcn_cvt_pk_fp8_f32(v.x, v.y, 0, false);
      q8 = __builtin_amdgcn_cvt_pk_fp8_f32(v.z, v.w, q8, true);
      xq[g] = (unsigned)q8;
    }
    return;
  }
  // ---- build block
  const int node0 = b << BSHIFT;
  const int nb = min(128, N - node0);
  const int ecount = min(bcnt[b * BPAD], BCAP);
  const unsigned* __restrict__ ed = edg + (size_t)b * BCAP;
  if (t < 128) lcnt[t] = 0;
  __syncthreads();
  for (int j = t; j < ecount; j += 1024)
    atomicAdd(&lcnt[ed[j] >> 17], 1);
  __syncthreads();
  // exclusive scan of PADDED degrees (pad-to-16), 1 node/thread, waves 0-1
  int incl = 0, pad = 0;
  if (t < 128) {
    int c = lcnt[t];
    pad = (c + 15) & ~15;
    incl = pad;
    int lane = t & 63;
#pragma unroll
    for (int off = 1; off < 64; off <<= 1) {
      int v = __shfl_up(incl, off, 64);
      if (lane >= off) incl += v;
    }
    if (lane == 63) wsum[t >> 6] = incl;
  }
  __syncthreads();  // uniform barrier (all 1024 threads of this block)
  if (t < 128) {
    int wv = t >> 6;
    int woff = (wv == 1) ? wsum[0] : 0;
    int excl = woff + incl - pad;
    lstart[t] = excl; lcur[t] = excl;
  }
  __syncthreads();
  for (int j = t; j < ecount; j += 1024) {
    unsigned e = ed[j];
    int p = atomicAdd(&lcur[e >> 17], 1);
    lsrc[p] = (int)(e & 0x1FFFFu);
  }
  // pad-fill: slots [start+cnt, start+padded) are disjoint from scatter
  // targets -> safe to run concurrently with the scatter loop above.
  if (t < 128) {
    int c = lcnt[t];
    int s0 = lstart[t] + c;
    int s1 = lstart[t] + ((c + 15) & ~15);
    for (int j = s0; j < s1; ++j) lsrc[j] = ZR;
  }
  __syncthreads();
  const int ebase = b * BCAP;  // BCAP % 16 == 0 -> rowstart stays 16-aligned
  int tot = wsum[0] + wsum[1];
  int ecountp = min(tot, BCAP);
  for (int j = 4 * t; j < ecountp; j += 4096) {  // int4 copy-out
    int4 v = *(const int4*)&lsrc[j];
    *(int4*)&eidx[ebase + j] = v;
  }
  if (t < nb) {
    rowcnt[2 * (node0 + t)]     = ebase + lstart[t];
    rowcnt[2 * (node0 + t) + 1] = lcnt[t];
  }
}

// ---------------------------------------------------------------- agg1 (fp8)
// NODE-PER-SUBGROUP: each 16-lane subgroup owns ONE node (4 nodes/wave),
// iterating its own edge list 4-at-a-time. Zero cross-lane reduction; the
// scale/f2b/store epilogue runs on all 64 lanes. 256-thread blocks
// (round-5: monolithic 1024-thread blocks strand finished waves).
__global__ __launch_bounds__(256) void k_agg1(
    const int* __restrict__ eidx, const int* __restrict__ rowcnt,
    const unsigned* __restrict__ xq, unsigned short* __restrict__ aggb, int N) {
  int wv = (blockIdx.x * 256 + threadIdx.x) >> 6;   // global wave id
  int lane = threadIdx.x & 63;
  const int sub = lane >> 4;      // which of the wave's 4 nodes
  const int li  = lane & 15;      // 8-B chunk of the 128-B fp8 row
  int n = wv * 4 + sub;
  const bool act = (n < N);
  int deg = 0;
  const int* el = eidx;
  if (act) {
    int2 rc = *(const int2*)(rowcnt + 2 * (size_t)n);
    deg = rc.y;
    el = eidx + rc.x;             // 16-int aligned (padded CSR)
  }
  f32x2 acc[4];
#pragma unroll
  for (int j = 0; j < 4; ++j) acc[j] = (f32x2){0.f, 0.f};

  for (int e = 0; e < deg; e += 4) {  // tail reads pad slots (ZR row = 0)
    int4 q = *(const int4*)(el + e);
    uint2 v0 = *(const uint2*)(xq + (size_t)q.x * 32 + li * 2);
    uint2 v1 = *(const uint2*)(xq + (size_t)q.y * 32 + li * 2);
    uint2 v2 = *(const uint2*)(xq + (size_t)q.z * 32 + li * 2);
    uint2 v3 = *(const uint2*)(xq + (size_t)q.w * 32 + li * 2);
#define ADD8(v)                                                      \
    acc[0] += __builtin_amdgcn_cvt_pk_f32_fp8(v.x, false);           \
    acc[1] += __builtin_amdgcn_cvt_pk_f32_fp8(v.x, true);            \
    acc[2] += __builtin_amdgcn_cvt_pk_f32_fp8(v.y, false);           \
    acc[3] += __builtin_amdgcn_cvt_pk_f32_fp8(v.y, true);
    ADD8(v0) ADD8(v1) ADD8(v2) ADD8(v3)
#undef ADD8
  }
  if (act) {
    float sc = 1.0f / (float)max(deg, 1);
    uint4 o4;  // lane li holds features [li*8, li*8+8): pack 8 bf16
    o4.x = (unsigned)f2b(acc[0].x * sc) | ((unsigned)f2b(acc[0].y * sc) << 16);
    o4.y = (unsigned)f2b(acc[1].x * sc) | ((unsigned)f2b(acc[1].y * sc) << 16);
    o4.z = (unsigned)f2b(acc[2].x * sc) | ((unsigned)f2b(acc[2].y * sc) << 16);
    o4.w = (unsigned)f2b(acc[3].x * sc) | ((unsigned)f2b(acc[3].y * sc) << 16);
    *(uint4*)(aggb + (size_t)n * 128 + li * 8) = o4;
  }
}

// ---------------------------------------------------------------- gemm1+2 MFMA
// h = relu([aggb | xb] @ Wb^T + b1) (K=256), then FUSED second GEMM via
// LDS round-trip (C-layout -> A-layout): Pnb = bf16(h @ Mb[0:16]^T),
// Ps = h @ Mb[16:32]^T. Mb B-frags loaded from global (8 KB, L2-hot).
__global__ __launch_bounds__(256) void k_gemm1_mfma(
    const unsigned short* __restrict__ aggb, const unsigned short* __restrict__ xb,
    const unsigned short* __restrict__ Wb, const float* __restrict__ b1,
    const unsigned short* __restrict__ Mb,
    unsigned short* __restrict__ Pnb, float* __restrict__ Ps, int N) {
  __shared__ union {
    struct { unsigned short A[128 * 40]; unsigned short W[128 * 40]; } s;
    unsigned short H[128 * 136];  // 34.8 KB h-tile, stride 136 (16B-aligned)
  } sm;
  const int t = threadIdx.x;
  const int w = t >> 6;
  const int lane = t & 63;
  const int q = lane >> 4;       // k-quad of the fragment
  const int l16 = lane & 15;
  const int row0 = blockIdx.x * 128;

  f32x4 acc[2][8];
#pragma unroll
  for (int rt = 0; rt < 2; ++rt)
#pragma unroll
    for (int ct = 0; ct < 8; ++ct) acc[rt][ct] = (f32x4){0.f, 0.f, 0.f, 0.f};

  for (int kc = 0; kc < 8; ++kc) {
    const unsigned short* Asrc = (kc < 4) ? aggb : xb;
    const int koff = (kc & 3) * 32;
#pragma unroll
    for (int i = 0; i < 2; ++i) {  // stage A: 128 rows x 32 k (8 KB)
      int idx = t + i * 256;
      int row = idx >> 2, c4 = idx & 3;
      int gr = row0 + row; if (gr >= N) gr = N - 1;
      uint4 v = *(const uint4*)(Asrc + (size_t)gr * 128 + koff + c4 * 8);
      *(uint4*)(sm.s.A + row * 40 + c4 * 8) = v;
    }
#pragma unroll
    for (int i = 0; i < 2; ++i) {  // stage W: 128 cols x 32 k (8 KB)
      int idx = t + i * 256;
      int col = idx >> 2, c4 = idx & 3;
      uint4 v = *(const uint4*)(Wb + col * 256 + kc * 32 + c4 * 8);
      *(uint4*)(sm.s.W + col * 40 + c4 * 8) = v;
    }
    __syncthreads();
    bf16x8 afr[2];
#pragma unroll
    for (int rt = 0; rt < 2; ++rt)
      afr[rt] = *(const bf16x8*)(sm.s.A + (w * 32 + rt * 16 + l16) * 40 + q * 8);
    bf16x8 bfr[8];
#pragma unroll
    for (int ct = 0; ct < 8; ++ct)
      bfr[ct] = *(const bf16x8*)(sm.s.W + (ct * 16 + l16) * 40 + q * 8);
#pragma unroll
    for (int rt = 0; rt < 2; ++rt)
#pragma unroll
      for (int ct = 0; ct < 8; ++ct)
        acc[rt][ct] = __builtin_amdgcn_mfma_f32_16x16x32_bf16(
            afr[rt], bfr[ct], acc[rt][ct], 0, 0, 0);
    __syncthreads();
  }

  // epilogue 1: bias + relu, h tile -> LDS (bf16, C-layout row = q*4+reg)
  float bv[8];
#pragma unroll
  for (int ct = 0; ct < 8; ++ct) bv[ct] = b1[ct * 16 + l16];
#pragma unroll
  for (int rt = 0; rt < 2; ++rt) {
    int rl = w * 32 + rt * 16 + q * 4;
#pragma unroll
    for (int reg = 0; reg < 4; ++reg) {
#pragma unroll
      for (int ct = 0; ct < 8; ++ct) {
        float v = acc[rt][ct][reg] + bv[ct];
        sm.H[(rl + reg) * 136 + ct * 16 + l16] = f2b(v > 0.f ? v : 0.f);
      }
    }
  }
  __syncthreads();

  // fused GEMM2: P(128x32) = h(128x128) @ Mb(32x128)^T, K=128 in 4 steps
  f32x4 acc2[2][2];
#pragma unroll
  for (int rt = 0; rt < 2; ++rt)
#pragma unroll
    for (int ct = 0; ct < 2; ++ct) acc2[rt][ct] = (f32x4){0.f, 0.f, 0.f, 0.f};
#pragma unroll
  for (int ks = 0; ks < 4; ++ks) {
    bf16x8 a2[2], b2v[2];
#pragma unroll
    for (int rt = 0; rt < 2; ++rt)
      a2[rt] = *(const bf16x8*)(sm.H + (w * 32 + rt * 16 + l16) * 136 + ks * 32 + q * 8);
#pragma unroll
    for (int ct = 0; ct < 2; ++ct)
      b2v[ct] = *(const bf16x8*)(Mb + (size_t)(ct * 16 + l16) * 128 + ks * 32 + q * 8);
#pragma unroll
    for (int rt = 0; rt < 2; ++rt)
#pragma unroll
      for (int ct = 0; ct < 2; ++ct)
        acc2[rt][ct] = __builtin_amdgcn_mfma_f32_16x16x32_bf16(
            a2[rt], b2v[ct], acc2[rt][ct], 0, 0, 0);
  }
#pragma unroll
  for (int rt = 0; rt < 2; ++rt) {
    int rbase = row0 + w * 32 + rt * 16 + q * 4;
#pragma unroll
    for (int reg = 0; reg < 4; ++reg) {
      int r = rbase + reg;
      Pnb[(size_t)r * 16 + l16] = f2b(acc2[rt][0][reg]);
      Ps[(size_t)r * 16 + l16] = acc2[rt][1][reg];
    }
  }
}

// out[i] = mean_nbr(Pnb[src]) + Ps[i] + bias2. One wave/node, padded CSR.
// sub=lane>>2 (16 edges), li=lane&3 (uint2 chunk of the 32 B bf16 row).
// Per-subgroup skip for all-pad slots. 256-thread blocks.
__global__ __launch_bounds__(256) void k_agg2_out(
    const int* __restrict__ eidx, const int* __restrict__ rowcnt,
    const unsigned short* __restrict__ Pnb, const float* __restrict__ Ps,
    const float* __restrict__ bias2, float* __restrict__ out, int N) {
  int i = (blockIdx.x * 256 + threadIdx.x) >> 6;
  int lane = threadIdx.x & 63;
  if (i >= N) return;
  const int sub = lane >> 2;
  const int li = lane & 3;
  int2 rc = *(const int2*)(rowcnt + 2 * (size_t)i);
  int deg = rc.y;
  const int* el = eidx + rc.x;
  f32x2 a0 = (f32x2){0.f, 0.f}, a1 = (f32x2){0.f, 0.f};
  for (int e = 0; e < deg; e += 16) {
    if (e + sub < deg) {  // slot is a real edge (pad slots contribute 0)
      int idx = el[e + sub];
      uint2 v = *(const uint2*)(Pnb + (size_t)idx * 16 + li * 4);
      a0 += (f32x2){b2f_lo(v.x), b2f_hi(v.x)};
      a1 += (f32x2){b2f_lo(v.y), b2f_hi(v.y)};
    }
  }
#pragma unroll
  for (int m = 4; m <= 32; m <<= 1) {
    a0.x += __shfl_xor(a0.x, m, 64);
    a0.y += __shfl_xor(a0.y, m, 64);
    a1.x += __shfl_xor(a1.x, m, 64);
    a1.y += __shfl_xor(a1.y, m, 64);
  }
  if (sub == 0) {
    float sc = 1.0f / (float)max(deg, 1);
    float4 self = *(const float4*)(Ps + (size_t)i * 16 + li * 4);
    float4 b = *(const float4*)(bias2 + li * 4);
    float4 o;
    o.x = a0.x * sc + self.x + b.x;
    o.y = a0.y * sc + self.y + b.y;
    o.z = a1.x * sc + self.z + b.z;
    o.w = a1.y * sc + self.w + b.w;
    *(float4*)(out + (size_t)i * 16 + li * 4) = o;
  }
}

extern "C" void kernel_launch(void* const* d_in, const int* in_sizes, int n_in,
                              void* d_out, int out_size, void* d_ws, size_t ws_size,
                              hipStream_t stream) {
  const float* x   = (const float*)d_in[0];
  const int*   ei  = (const int*)d_in[1];
  const float* W1l = (const float*)d_in[2];
  const float* b1l = (const float*)d_in[3];
  const float* W1r = (const float*)d_in[4];
  const float* W2l = (const float*)d_in[5];
  const float* b2l = (const float*)d_in[6];
  const float* W2r = (const float*)d_in[7];
  const float* Wc  = (const float*)d_in[8];
  const float* bc  = (const float*)d_in[9];
  float* out = (float*)d_out;

  const int N      = in_sizes[0] / 128;
  const int E      = in_sizes[1] / 2;
  const int Np     = ((N + 127) / 128) * 128;  // pad to 128-row GEMM tiles
  const int NBUCK  = (N + 127) >> BSHIFT;
  const int ZR     = Np;                       // zero-row index (xb/xq/Pnb)
  const int NBIN   = (E + CHUNK - 1) / CHUNK;
  const int NCAST  = (N * 32 + 1023) / 1024;   // cast blocks @ 1024 thr

  char* ws = (char*)d_ws;
  size_t off = 0;
  auto alloc = [&](size_t bytes) {
    void* p = ws + off;
    off = (off + bytes + 255) & ~(size_t)255;
    return p;
  };
  int*            rowcnt   = (int*)           alloc((size_t)N * 8);
  int*            bcnt     = (int*)           alloc((size_t)MAXB * BPAD * 4);
  unsigned*       edg      = (unsigned*)      alloc((size_t)NBUCK * BCAP * 4);
  int*            eidx     = (int*)           alloc((size_t)NBUCK * BCAP * 4);
  unsigned short* xb       = (unsigned short*)alloc((size_t)(Np + 1) * 128 * 2);
  unsigned*       xq       = (unsigned*)      alloc((size_t)(Np + 1) * 32 * 4);
  unsigned short* aggb     = (unsigned short*)alloc((size_t)Np * 128 * 2);
  unsigned short* Wb       = (unsigned short*)alloc((size_t)128 * 256 * 2);
  unsigned short* Mb       = (unsigned short*)alloc((size_t)32 * 128 * 2);
  unsigned short* Pnb      = (unsigned short*)alloc((size_t)(Np + 1) * 16 * 2);
  float*          Ps       = (float*)         alloc((size_t)Np * 16 * 4);
  float*          bias2    = (float*)         alloc(16 * 4);
  (void)ws_size; (void)n_in; (void)out_size;

  hipMemsetAsync(bcnt, 0, (size_t)MAXB * BPAD * 4, stream);
  k_bin<<<NBIN + 145, 1024, 0, stream>>>(
      ei, E, bcnt, edg,
      W1l, W1r, Wb, Wc, bc, W2l, W2r, b2l, Mb, bias2, xb, xq, Pnb, ZR, NBIN);
  k_buildcast<<<NBUCK + NCAST, 1024, 0, stream>>>(
      edg, bcnt, eidx, rowcnt, N, ZR, NBUCK, x, xb, xq, N * 32);
  k_agg1<<<(N + 15) / 16, 256, 0, stream>>>(eidx, rowcnt, xq, aggb, N);
  k_gemm1_mfma<<<Np / 128, 256, 0, stream>>>(aggb, xb, Wb, b1l, Mb, Pnb, Ps, N);
  k_agg2_out<<<(N + 3) / 4, 256, 0, stream>>>(eidx, rowcnt, Pnb, Ps, bias2, out, N);
}

// Round 11
// 216.876 us; speedup vs baseline: 1.1198x; 1.1198x over previous
//
#include <hip/hip_runtime.h>

#define BSHIFT 8            // bucket = dst >> 8 (256 nodes/bucket)  [r9 proven]
#define MAXB   512          // max buckets supported by hist arrays
#define BPAD   16           // bcnt line padding: one counter per 64 B line
#define BCAP   6912         // padded edges/bucket (mean ~6.0k incl pad-to-16, ~+7 sigma)
#define CHUNK  8192         // edges per k_bin block (32 KB LDS stage, 1024 thr)

typedef __bf16 bf16x8 __attribute__((ext_vector_type(8)));
typedef float  f32x4  __attribute__((ext_vector_type(4)));
typedef float  f32x2  __attribute__((ext_vector_type(2)));

__device__ __forceinline__ unsigned short f2b(float f) {  // fp32 -> bf16 RNE
  unsigned u = __float_as_uint(f);
  return (unsigned short)((u + 0x7fffu + ((u >> 16) & 1u)) >> 16);
}
__device__ __forceinline__ float b2f_lo(unsigned u) {  // low bf16 of packed pair
  return __uint_as_float(u << 16);
}
__device__ __forceinline__ float b2f_hi(unsigned u) {
  return __uint_as_float(u & 0xffff0000u);
}

// ---------------------------------------------------------------- bin (+fold)
// [0,nbin): bin edges into buckets (packed uint: dloc<<17|src). 1024 thr,
// 38 KB LDS. bcnt line-padded (stride BPAD). CHUNK=8192/BSHIFT=8 is the r9
// proven config (r10's 4096/BSHIFT=7 regressed: doubled fixed overhead +
// higher per-counter LDS atomic contention).
// [nbin,nbin+145): castW / layer-2 fold / zero rows, gated to t<256.
__global__ __launch_bounds__(1024) void k_bin(
    const int* __restrict__ ei, int E, int* __restrict__ bcnt,
    unsigned* __restrict__ edg,
    const float* __restrict__ W1l, const float* __restrict__ W1r,
    unsigned short* __restrict__ Wb,
    const float* __restrict__ Wc, const float* __restrict__ bc,
    const float* __restrict__ W2l, const float* __restrict__ W2r,
    const float* __restrict__ b2, unsigned short* __restrict__ Mb,
    float* __restrict__ bias2,
    unsigned short* __restrict__ xb, unsigned* __restrict__ xq,
    unsigned short* __restrict__ Pnb, int ZR, int nbin) {
  __shared__ int lh[MAXB], lbase[MAXB], lcur[MAXB];   // 6 KB
  __shared__ int ldst[CHUNK];                         // 32 KB dst stage
  const int b = blockIdx.x;
  const int t = threadIdx.x;
  if (b < nbin) {
    for (int i = t; i < MAXB; i += 1024) { lh[i] = 0; lcur[i] = 0; }
    __syncthreads();
    const int e0 = b * CHUNK;
    const int n = min(E - e0, CHUNK);
    const int* __restrict__ src = ei;
    const int* __restrict__ dst = ei + E;
    for (int j = t; j < n; j += 1024) {
      int d = dst[e0 + j];
      ldst[j] = d;
      atomicAdd(&lh[((unsigned)d) >> BSHIFT], 1);
    }
    __syncthreads();
    for (int i = t; i < MAXB; i += 1024)
      if (lh[i]) lbase[i] = atomicAdd(&bcnt[i * BPAD], lh[i]);
    __syncthreads();
    for (int j = t; j < n; j += 1024) {
      int d = ldst[j];
      unsigned s = (unsigned)src[e0 + j];
      int bk = ((unsigned)d) >> BSHIFT;
      int p = lbase[bk] + atomicAdd(&lcur[bk], 1);
      if (p < BCAP) edg[(size_t)bk * BCAP + p] = ((unsigned)(d & 255) << 17) | s;
    }
  } else if (t < 256) {
    int bb = b - nbin;
    if (bb < 128) {
      int idx = bb * 256 + t;
      int col = idx >> 8, k = idx & 255;
      float v = (k < 128) ? W1l[col * 128 + k] : W1r[col * 128 + (k - 128)];
      Wb[col * 256 + k] = f2b(v);
    } else if (bb < 144) {
      int mb = bb - 128;
      int mat = mb >> 3;
      const float* W2 = mat ? W2r : W2l;
      int o = (mb & 7) * 2 + (t >> 7);
      int k = t & 127;
      float s = 0.f;
      for (int j = 0; j < 128; ++j) s = fmaf(Wc[o * 128 + j], W2[j * 128 + k], s);
      Mb[(size_t)(mat * 16 + o) * 128 + k] = f2b(s);
      if (mb == 0 && t < 16) {
        float sb = bc[t];
        for (int j = 0; j < 128; ++j) sb = fmaf(Wc[t * 128 + j], b2[j], sb);
        bias2[t] = sb;
      }
    } else {
      if (t < 64) ((unsigned*)(xb + (size_t)ZR * 128))[t] = 0;   // zero row (bf16)
      if (t < 32) xq[(size_t)ZR * 32 + t] = 0;                   // zero row (fp8)
      if (t < 8)  ((unsigned*)(Pnb + (size_t)ZR * 16))[t] = 0;   // zero row (bf16)
    }
  }
}

// ---------------------------------------------------------------- build ∥ cast
// [0,nbuck): per-bucket CSR finalize (degree hist + pad-to-16 scan + src
// scatter in LDS, coalesced int4 writes) — r9 proven form.
// [nbuck,...): streaming cast x -> bf16 xb + fp8 xq (independent of build,
// fills the CUs build leaves idle; graph capture forbids multi-stream).
__global__ __launch_bounds__(1024) void k_buildcast(
    const unsigned* __restrict__ edg, const int* __restrict__ bcnt,
    int* __restrict__ eidx, int* __restrict__ rowcnt, int N, int ZR,
    int nbuck, const float* __restrict__ x, unsigned short* __restrict__ xb,
    unsigned* __restrict__ xq, int ngroups) {
  __shared__ int lsrc[BCAP];                       // 27 KB
  __shared__ int lcnt[256], lstart[256], lcur[256];
  __shared__ int wsum[4];
  const int b = blockIdx.x;
  const int t = threadIdx.x;
  if (b >= nbuck) {                                // ---- cast block
    int g = (b - nbuck) * 1024 + t;
    if (g < ngroups) {
      float4 v = ((const float4*)x)[g];
      ushort4 o;
      o.x = f2b(v.x); o.y = f2b(v.y); o.z = f2b(v.z); o.w = f2b(v.w);
      ((ushort4*)xb)[g] = o;
      int q8 = __builtin_amdgcn_cvt_pk_fp8_f32(v.x, v.y, 0, false);
      q8 = __builtin_amdgcn_cvt_pk_fp8_f32(v.z, v.w, q8, true);
      xq[g] = (unsigned)q8;
    }
    return;
  }
  // ---- build block
  const int node0 = b << BSHIFT;
  const int nb = min(256, N - node0);
  const int ecount = min(bcnt[b * BPAD], BCAP);
  const unsigned* __restrict__ ed = edg + (size_t)b * BCAP;
  if (t < 256) lcnt[t] = 0;
  __syncthreads();
  for (int j = t; j < ecount; j += 1024)
    atomicAdd(&lcnt[ed[j] >> 17], 1);
  __syncthreads();
  // exclusive scan of PADDED degrees (pad-to-16), 1 node/thread, waves 0-3
  int incl = 0, pad = 0;
  if (t < 256) {
    int c = lcnt[t];
    pad = (c + 15) & ~15;
    incl = pad;
    int lane = t & 63;
#pragma unroll
    for (int off = 1; off < 64; off <<= 1) {
      int v = __shfl_up(incl, off, 64);
      if (lane >= off) incl += v;
    }
    if (lane == 63) wsum[t >> 6] = incl;
  }
  __syncthreads();  // uniform barrier (all 1024 threads of this block)
  if (t < 256) {
    int wv = t >> 6;
    int woff = 0;
    for (int i = 0; i < wv; ++i) woff += wsum[i];
    int excl = woff + incl - pad;
    lstart[t] = excl; lcur[t] = excl;
  }
  __syncthreads();
  for (int j = t; j < ecount; j += 1024) {
    unsigned e = ed[j];
    int p = atomicAdd(&lcur[e >> 17], 1);
    lsrc[p] = (int)(e & 0x1FFFFu);
  }
  // pad-fill: slots [start+cnt, start+padded) are disjoint from scatter
  // targets -> safe to run concurrently with the scatter loop above.
  if (t < 256) {
    int c = lcnt[t];
    int s0 = lstart[t] + c;
    int s1 = lstart[t] + ((c + 15) & ~15);
    for (int j = s0; j < s1; ++j) lsrc[j] = ZR;
  }
  __syncthreads();
  const int ebase = b * BCAP;  // BCAP % 16 == 0 -> rowstart stays 16-aligned
  int tot = wsum[0] + wsum[1] + wsum[2] + wsum[3];
  int ecountp = min(tot, BCAP);
  for (int j = 4 * t; j < ecountp; j += 4096) {  // int4 copy-out
    int4 v = *(const int4*)&lsrc[j];
    *(int4*)&eidx[ebase + j] = v;
  }
  if (t < nb) {
    rowcnt[2 * (node0 + t)]     = ebase + lstart[t];
    rowcnt[2 * (node0 + t) + 1] = lcnt[t];
  }
}

// ---------------------------------------------------------------- agg1 (fp8)
// NODE-PER-SUBGROUP: each 16-lane subgroup owns ONE node (4 nodes/wave),
// iterating its own edge list 4-at-a-time. Zero cross-lane reduction; the
// scale/f2b/store epilogue runs on all 64 lanes. 256-thread blocks
// (round-5: monolithic 1024-thread blocks strand finished waves).
__global__ __launch_bounds__(256) void k_agg1(
    const int* __restrict__ eidx, const int* __restrict__ rowcnt,
    const unsigned* __restrict__ xq, unsigned short* __restrict__ aggb, int N) {
  int wv = (blockIdx.x * 256 + threadIdx.x) >> 6;   // global wave id
  int lane = threadIdx.x & 63;
  const int sub = lane >> 4;      // which of the wave's 4 nodes
  const int li  = lane & 15;      // 8-B chunk of the 128-B fp8 row
  int n = wv * 4 + sub;
  const bool act = (n < N);
  int deg = 0;
  const int* el = eidx;
  if (act) {
    int2 rc = *(const int2*)(rowcnt + 2 * (size_t)n);
    deg = rc.y;
    el = eidx + rc.x;             // 16-int aligned (padded CSR)
  }
  f32x2 acc[4];
#pragma unroll
  for (int j = 0; j < 4; ++j) acc[j] = (f32x2){0.f, 0.f};

  for (int e = 0; e < deg; e += 4) {  // tail reads pad slots (ZR row = 0)
    int4 q = *(const int4*)(el + e);
    uint2 v0 = *(const uint2*)(xq + (size_t)q.x * 32 + li * 2);
    uint2 v1 = *(const uint2*)(xq + (size_t)q.y * 32 + li * 2);
    uint2 v2 = *(const uint2*)(xq + (size_t)q.z * 32 + li * 2);
    uint2 v3 = *(const uint2*)(xq + (size_t)q.w * 32 + li * 2);
#define ADD8(v)                                                      \
    acc[0] += __builtin_amdgcn_cvt_pk_f32_fp8(v.x, false);           \
    acc[1] += __builtin_amdgcn_cvt_pk_f32_fp8(v.x, true);            \
    acc[2] += __builtin_amdgcn_cvt_pk_f32_fp8(v.y, false);           \
    acc[3] += __builtin_amdgcn_cvt_pk_f32_fp8(v.y, true);
    ADD8(v0) ADD8(v1) ADD8(v2) ADD8(v3)
#undef ADD8
  }
  if (act) {
    float sc = 1.0f / (float)max(deg, 1);
    uint4 o4;  // lane li holds features [li*8, li*8+8): pack 8 bf16
    o4.x = (unsigned)f2b(acc[0].x * sc) | ((unsigned)f2b(acc[0].y * sc) << 16);
    o4.y = (unsigned)f2b(acc[1].x * sc) | ((unsigned)f2b(acc[1].y * sc) << 16);
    o4.z = (unsigned)f2b(acc[2].x * sc) | ((unsigned)f2b(acc[2].y * sc) << 16);
    o4.w = (unsigned)f2b(acc[3].x * sc) | ((unsigned)f2b(acc[3].y * sc) << 16);
    *(uint4*)(aggb + (size_t)n * 128 + li * 8) = o4;
  }
}

// ---------------------------------------------------------------- gemm1+2 MFMA
// h = relu([aggb | xb] @ Wb^T + b1) (K=256), then FUSED second GEMM via
// LDS round-trip (C-layout -> A-layout): Pnb = bf16(h @ Mb[0:16]^T),
// Ps = h @ Mb[16:32]^T. Mb B-frags loaded from global (8 KB, L2-hot).
__global__ __launch_bounds__(256) void k_gemm1_mfma(
    const unsigned short* __restrict__ aggb, const unsigned short* __restrict__ xb,
    const unsigned short* __restrict__ Wb, const float* __restrict__ b1,
    const unsigned short* __restrict__ Mb,
    unsigned short* __restrict__ Pnb, float* __restrict__ Ps, int N) {
  __shared__ union {
    struct { unsigned short A[128 * 40]; unsigned short W[128 * 40]; } s;
    unsigned short H[128 * 136];  // 34.8 KB h-tile, stride 136 (16B-aligned)
  } sm;
  const int t = threadIdx.x;
  const int w = t >> 6;
  const int lane = t & 63;
  const int q = lane >> 4;       // k-quad of the fragment
  const int l16 = lane & 15;
  const int row0 = blockIdx.x * 128;

  f32x4 acc[2][8];
#pragma unroll
  for (int rt = 0; rt < 2; ++rt)
#pragma unroll
    for (int ct = 0; ct < 8; ++ct) acc[rt][ct] = (f32x4){0.f, 0.f, 0.f, 0.f};

  for (int kc = 0; kc < 8; ++kc) {
    const unsigned short* Asrc = (kc < 4) ? aggb : xb;
    const int koff = (kc & 3) * 32;
#pragma unroll
    for (int i = 0; i < 2; ++i) {  // stage A: 128 rows x 32 k (8 KB)
      int idx = t + i * 256;
      int row = idx >> 2, c4 = idx & 3;
      int gr = row0 + row; if (gr >= N) gr = N - 1;
      uint4 v = *(const uint4*)(Asrc + (size_t)gr * 128 + koff + c4 * 8);
      *(uint4*)(sm.s.A + row * 40 + c4 * 8) = v;
    }
#pragma unroll
    for (int i = 0; i < 2; ++i) {  // stage W: 128 cols x 32 k (8 KB)
      int idx = t + i * 256;
      int col = idx >> 2, c4 = idx & 3;
      uint4 v = *(const uint4*)(Wb + col * 256 + kc * 32 + c4 * 8);
      *(uint4*)(sm.s.W + col * 40 + c4 * 8) = v;
    }
    __syncthreads();
    bf16x8 afr[2];
#pragma unroll
    for (int rt = 0; rt < 2; ++rt)
      afr[rt] = *(const bf16x8*)(sm.s.A + (w * 32 + rt * 16 + l16) * 40 + q * 8);
    bf16x8 bfr[8];
#pragma unroll
    for (int ct = 0; ct < 8; ++ct)
      bfr[ct] = *(const bf16x8*)(sm.s.W + (ct * 16 + l16) * 40 + q * 8);
#pragma unroll
    for (int rt = 0; rt < 2; ++rt)
#pragma unroll
      for (int ct = 0; ct < 8; ++ct)
        acc[rt][ct] = __builtin_amdgcn_mfma_f32_16x16x32_bf16(
            afr[rt], bfr[ct], acc[rt][ct], 0, 0, 0);
    __syncthreads();
  }

  // epilogue 1: bias + relu, h tile -> LDS (bf16, C-layout row = q*4+reg)
  float bv[8];
#pragma unroll
  for (int ct = 0; ct < 8; ++ct) bv[ct] = b1[ct * 16 + l16];
#pragma unroll
  for (int rt = 0; rt < 2; ++rt) {
    int rl = w * 32 + rt * 16 + q * 4;
#pragma unroll
    for (int reg = 0; reg < 4; ++reg) {
#pragma unroll
      for (int ct = 0; ct < 8; ++ct) {
        float v = acc[rt][ct][reg] + bv[ct];
        sm.H[(rl + reg) * 136 + ct * 16 + l16] = f2b(v > 0.f ? v : 0.f);
      }
    }
  }
  __syncthreads();

  // fused GEMM2: P(128x32) = h(128x128) @ Mb(32x128)^T, K=128 in 4 steps
  f32x4 acc2[2][2];
#pragma unroll
  for (int rt = 0; rt < 2; ++rt)
#pragma unroll
    for (int ct = 0; ct < 2; ++ct) acc2[rt][ct] = (f32x4){0.f, 0.f, 0.f, 0.f};
#pragma unroll
  for (int ks = 0; ks < 4; ++ks) {
    bf16x8 a2[2], b2v[2];
#pragma unroll
    for (int rt = 0; rt < 2; ++rt)
      a2[rt] = *(const bf16x8*)(sm.H + (w * 32 + rt * 16 + l16) * 136 + ks * 32 + q * 8);
#pragma unroll
    for (int ct = 0; ct < 2; ++ct)
      b2v[ct] = *(const bf16x8*)(Mb + (size_t)(ct * 16 + l16) * 128 + ks * 32 + q * 8);
#pragma unroll
    for (int rt = 0; rt < 2; ++rt)
#pragma unroll
      for (int ct = 0; ct < 2; ++ct)
        acc2[rt][ct] = __builtin_amdgcn_mfma_f32_16x16x32_bf16(
            a2[rt], b2v[ct], acc2[rt][ct], 0, 0, 0);
  }
#pragma unroll
  for (int rt = 0; rt < 2; ++rt) {
    int rbase = row0 + w * 32 + rt * 16 + q * 4;
#pragma unroll
    for (int reg = 0; reg < 4; ++reg) {
      int r = rbase + reg;
      Pnb[(size_t)r * 16 + l16] = f2b(acc2[rt][0][reg]);
      Ps[(size_t)r * 16 + l16] = acc2[rt][1][reg];
    }
  }
}

// ---------------------------------------------------------------- agg2 + out
// NODE-PER-SUBGROUP (r6 agg1 pattern ported): each 4-lane subgroup owns ONE
// node (16 nodes/wave); its 4 lanes hold the node's 32-B Pnb row (uint2 per
// lane). Per iter: one broadcast int4 edge load + 4 uint2 gathers. ZERO
// cross-lane reduction (old form: 16 shfl_xor + 16 adds per node = ~20x the
// gather issue cost); scale/self/bias epilogue on all 64 lanes (was 4/64).
// Pad slots read ZR (zero row) -> contribute 0, loop is unconditional.
__global__ __launch_bounds__(256) void k_agg2_out(
    const int* __restrict__ eidx, const int* __restrict__ rowcnt,
    const unsigned short* __restrict__ Pnb, const float* __restrict__ Ps,
    const float* __restrict__ bias2, float* __restrict__ out, int N) {
  int wv = (blockIdx.x * 256 + threadIdx.x) >> 6;   // global wave id
  int lane = threadIdx.x & 63;
  const int sub = lane >> 2;      // which of the wave's 16 nodes
  const int li  = lane & 3;       // 8-B chunk of the 32-B bf16 row
  int n = wv * 16 + sub;
  const bool act = (n < N);
  int deg = 0;
  const int* el = eidx;
  if (act) {
    int2 rc = *(const int2*)(rowcnt + 2 * (size_t)n);
    deg = rc.y;
    el = eidx + rc.x;             // 16-int aligned (padded CSR)
  }
  f32x2 a0 = (f32x2){0.f, 0.f}, a1 = (f32x2){0.f, 0.f};
  for (int e = 0; e < deg; e += 4) {  // tail reads pad slots (ZR row = 0)
    int4 q = *(const int4*)(el + e);  // broadcast across the sub's 4 lanes
    uint2 v0 = *(const uint2*)(Pnb + (size_t)q.x * 16 + li * 4);
    uint2 v1 = *(const uint2*)(Pnb + (size_t)q.y * 16 + li * 4);
    uint2 v2 = *(const uint2*)(Pnb + (size_t)q.z * 16 + li * 4);
    uint2 v3 = *(const uint2*)(Pnb + (size_t)q.w * 16 + li * 4);
#define ACC2(v)                                   \
    a0 += (f32x2){b2f_lo(v.x), b2f_hi(v.x)};      \
    a1 += (f32x2){b2f_lo(v.y), b2f_hi(v.y)};
    ACC2(v0) ACC2(v1) ACC2(v2) ACC2(v3)
#undef ACC2
  }
  if (act) {
    float sc = 1.0f / (float)max(deg, 1);
    float4 self = *(const float4*)(Ps + (size_t)n * 16 + li * 4);
    float4 b = *(const float4*)(bias2 + li * 4);
    float4 o;
    o.x = a0.x * sc + self.x + b.x;
    o.y = a0.y * sc + self.y + b.y;
    o.z = a1.x * sc + self.z + b.z;
    o.w = a1.y * sc + self.w + b.w;
    *(float4*)(out + (size_t)n * 16 + li * 4) = o;
  }
}

extern "C" void kernel_launch(void* const* d_in, const int* in_sizes, int n_in,
                              void* d_out, int out_size, void* d_ws, size_t ws_size,
                              hipStream_t stream) {
  const float* x   = (const float*)d_in[0];
  const int*   ei  = (const int*)d_in[1];
  const float* W1l = (const float*)d_in[2];
  const float* b1l = (const float*)d_in[3];
  const float* W1r = (const float*)d_in[4];
  const float* W2l = (const float*)d_in[5];
  const float* b2l = (const float*)d_in[6];
  const float* W2r = (const float*)d_in[7];
  const float* Wc  = (const float*)d_in[8];
  const float* bc  = (const float*)d_in[9];
  float* out = (float*)d_out;

  const int N      = in_sizes[0] / 128;
  const int E      = in_sizes[1] / 2;
  const int Np     = ((N + 127) / 128) * 128;  // pad to 128-row GEMM tiles
  const int NBUCK  = (N + 255) >> BSHIFT;
  const int ZR     = Np;                       // zero-row index (xb/xq/Pnb)
  const int NBIN   = (E + CHUNK - 1) / CHUNK;
  const int NCAST  = (N * 32 + 1023) / 1024;   // cast blocks @ 1024 thr

  char* ws = (char*)d_ws;
  size_t off = 0;
  auto alloc = [&](size_t bytes) {
    void* p = ws + off;
    off = (off + bytes + 255) & ~(size_t)255;
    return p;
  };
  int*            rowcnt   = (int*)           alloc((size_t)N * 8);
  int*            bcnt     = (int*)           alloc((size_t)MAXB * BPAD * 4);
  unsigned*       edg      = (unsigned*)      alloc((size_t)NBUCK * BCAP * 4);
  int*            eidx     = (int*)           alloc((size_t)NBUCK * BCAP * 4);
  unsigned short* xb       = (unsigned short*)alloc((size_t)(Np + 1) * 128 * 2);
  unsigned*       xq       = (unsigned*)      alloc((size_t)(Np + 1) * 32 * 4);
  unsigned short* aggb     = (unsigned short*)alloc((size_t)Np * 128 * 2);
  unsigned short* Wb       = (unsigned short*)alloc((size_t)128 * 256 * 2);
  unsigned short* Mb       = (unsigned short*)alloc((size_t)32 * 128 * 2);
  unsigned short* Pnb      = (unsigned short*)alloc((size_t)(Np + 1) * 16 * 2);
  float*          Ps       = (float*)         alloc((size_t)Np * 16 * 4);
  float*          bias2    = (float*)         alloc(16 * 4);
  (void)ws_size; (void)n_in; (void)out_size;

  hipMemsetAsync(bcnt, 0, (size_t)MAXB * BPAD * 4, stream);
  k_bin<<<NBIN + 145, 1024, 0, stream>>>(
      ei, E, bcnt, edg,
      W1l, W1r, Wb, Wc, bc, W2l, W2r, b2l, Mb, bias2, xb, xq, Pnb, ZR, NBIN);
  k_buildcast<<<NBUCK + NCAST, 1024, 0, stream>>>(
      edg, bcnt, eidx, rowcnt, N, ZR, NBUCK, x, xb, xq, N * 32);
  k_agg1<<<(N + 15) / 16, 256, 0, stream>>>(eidx, rowcnt, xq, aggb, N);
  k_gemm1_mfma<<<Np / 128, 256, 0, stream>>>(aggb, xb, Wb, b1l, Mb, Pnb, Ps, N);
  k_agg2_out<<<(N + 63) / 64, 256, 0, stream>>>(eidx, rowcnt, Pnb, Ps, bias2, out, N);
}

// Round 12
// 215.986 us; speedup vs baseline: 1.1245x; 1.0041x over previous
//
#include <hip/hip_runtime.h>

#define BSHIFT 8            // bucket = dst >> 8 (256 nodes/bucket)  [r9 proven]
#define MAXB   512          // max buckets supported by hist arrays
#define BPAD   16           // bcnt line padding: one counter per 64 B line
#define BCAP   6912         // padded edges/bucket (mean ~6.0k incl pad-to-16, ~+7 sigma)
#define CHUNK  8192         // edges per k_bin block (32 KB LDS stage, 1024 thr)
#define CAST1  1300         // cast blocks riding k_bin's idle slots (~bin shadow)

typedef __bf16 bf16x8 __attribute__((ext_vector_type(8)));
typedef float  f32x4  __attribute__((ext_vector_type(4)));
typedef float  f32x2  __attribute__((ext_vector_type(2)));

__device__ __forceinline__ unsigned short f2b(float f) {  // fp32 -> bf16 RNE
  unsigned u = __float_as_uint(f);
  return (unsigned short)((u + 0x7fffu + ((u >> 16) & 1u)) >> 16);
}
__device__ __forceinline__ float b2f_lo(unsigned u) {  // low bf16 of packed pair
  return __uint_as_float(u << 16);
}
__device__ __forceinline__ float b2f_hi(unsigned u) {
  return __uint_as_float(u & 0xffff0000u);
}

__device__ __forceinline__ void cast_group(
    const float* __restrict__ x, unsigned short* __restrict__ xb,
    unsigned* __restrict__ xq, int g, int ngroups) {
  if (g < ngroups) {
    float4 v = ((const float4*)x)[g];
    ushort4 o;
    o.x = f2b(v.x); o.y = f2b(v.y); o.z = f2b(v.z); o.w = f2b(v.w);
    ((ushort4*)xb)[g] = o;
    int q8 = __builtin_amdgcn_cvt_pk_fp8_f32(v.x, v.y, 0, false);
    q8 = __builtin_amdgcn_cvt_pk_fp8_f32(v.z, v.w, q8, true);
    xq[g] = (unsigned)q8;
  }
}

// ---------------------------------------------------------------- bin (+fold ∥ cast)
// [0,nbin): bin edges into buckets (packed uint: dloc<<17|src). 1024 thr,
// 38 KB LDS. bcnt line-padded (stride BPAD). r9-proven geometry.
// [nbin,nbin+145): castW / layer-2 fold / zero rows, gated to t<256.
// [nbin+145,...): first CAST1 cast blocks — bin uses only 341 of 512 block
// slots (33% of the machine idle for bin's ~40 µs); cast is independent of
// bin, so it rides the idle slots (round-12 overlap).
__global__ __launch_bounds__(1024) void k_bin(
    const int* __restrict__ ei, int E, int* __restrict__ bcnt,
    unsigned* __restrict__ edg,
    const float* __restrict__ W1l, const float* __restrict__ W1r,
    unsigned short* __restrict__ Wb,
    const float* __restrict__ Wc, const float* __restrict__ bc,
    const float* __restrict__ W2l, const float* __restrict__ W2r,
    const float* __restrict__ b2, unsigned short* __restrict__ Mb,
    float* __restrict__ bias2,
    unsigned short* __restrict__ xb, unsigned* __restrict__ xq,
    unsigned short* __restrict__ Pnb, int ZR, int nbin,
    const float* __restrict__ x, int ngroups) {
  __shared__ int lh[MAXB], lbase[MAXB], lcur[MAXB];   // 6 KB
  __shared__ int ldst[CHUNK];                         // 32 KB dst stage
  const int b = blockIdx.x;
  const int t = threadIdx.x;
  if (b < nbin) {
    for (int i = t; i < MAXB; i += 1024) { lh[i] = 0; lcur[i] = 0; }
    __syncthreads();
    const int e0 = b * CHUNK;
    const int n = min(E - e0, CHUNK);
    const int* __restrict__ src = ei;
    const int* __restrict__ dst = ei + E;
    for (int j = t; j < n; j += 1024) {
      int d = dst[e0 + j];
      ldst[j] = d;
      atomicAdd(&lh[((unsigned)d) >> BSHIFT], 1);
    }
    __syncthreads();
    for (int i = t; i < MAXB; i += 1024)
      if (lh[i]) lbase[i] = atomicAdd(&bcnt[i * BPAD], lh[i]);
    __syncthreads();
    for (int j = t; j < n; j += 1024) {
      int d = ldst[j];
      unsigned s = (unsigned)src[e0 + j];
      int bk = ((unsigned)d) >> BSHIFT;
      int p = lbase[bk] + atomicAdd(&lcur[bk], 1);
      if (p < BCAP) edg[(size_t)bk * BCAP + p] = ((unsigned)(d & 255) << 17) | s;
    }
  } else if (b < nbin + 145) {
    if (t < 256) {
      int bb = b - nbin;
      if (bb < 128) {
        int idx = bb * 256 + t;
        int col = idx >> 8, k = idx & 255;
        float v = (k < 128) ? W1l[col * 128 + k] : W1r[col * 128 + (k - 128)];
        Wb[col * 256 + k] = f2b(v);
      } else if (bb < 144) {
        int mb = bb - 128;
        int mat = mb >> 3;
        const float* W2 = mat ? W2r : W2l;
        int o = (mb & 7) * 2 + (t >> 7);
        int k = t & 127;
        float s = 0.f;
        for (int j = 0; j < 128; ++j) s = fmaf(Wc[o * 128 + j], W2[j * 128 + k], s);
        Mb[(size_t)(mat * 16 + o) * 128 + k] = f2b(s);
        if (mb == 0 && t < 16) {
          float sb = bc[t];
          for (int j = 0; j < 128; ++j) sb = fmaf(Wc[t * 128 + j], b2[j], sb);
          bias2[t] = sb;
        }
      } else {
        if (t < 64) ((unsigned*)(xb + (size_t)ZR * 128))[t] = 0;   // zero row (bf16)
        if (t < 32) xq[(size_t)ZR * 32 + t] = 0;                   // zero row (fp8)
        if (t < 8)  ((unsigned*)(Pnb + (size_t)ZR * 16))[t] = 0;   // zero row (bf16)
      }
    }
  } else {
    cast_group(x, xb, xq, (b - nbin - 145) * 1024 + t, ngroups);
  }
}

// ---------------------------------------------------------------- build ∥ cast
// [0,nbuck): per-bucket CSR finalize (degree hist + pad-to-16 scan + src
// scatter in LDS, coalesced int4 writes) — r9 proven form.
// [nbuck,...): remaining cast blocks (offset CAST1 already done in k_bin),
// filling the CUs build leaves idle (391 blocks = 1.5/CU).
__global__ __launch_bounds__(1024) void k_buildcast(
    const unsigned* __restrict__ edg, const int* __restrict__ bcnt,
    int* __restrict__ eidx, int* __restrict__ rowcnt, int N, int ZR,
    int nbuck, const float* __restrict__ x, unsigned short* __restrict__ xb,
    unsigned* __restrict__ xq, int ngroups, int castbase) {
  __shared__ int lsrc[BCAP];                       // 27 KB
  __shared__ int lcnt[256], lstart[256], lcur[256];
  __shared__ int wsum[4];
  const int b = blockIdx.x;
  const int t = threadIdx.x;
  if (b >= nbuck) {                                // ---- cast block
    cast_group(x, xb, xq, (castbase + b - nbuck) * 1024 + t, ngroups);
    return;
  }
  // ---- build block
  const int node0 = b << BSHIFT;
  const int nb = min(256, N - node0);
  const int ecount = min(bcnt[b * BPAD], BCAP);
  const unsigned* __restrict__ ed = edg + (size_t)b * BCAP;
  if (t < 256) lcnt[t] = 0;
  __syncthreads();
  for (int j = t; j < ecount; j += 1024)
    atomicAdd(&lcnt[ed[j] >> 17], 1);
  __syncthreads();
  // exclusive scan of PADDED degrees (pad-to-16), 1 node/thread, waves 0-3
  int incl = 0, pad = 0;
  if (t < 256) {
    int c = lcnt[t];
    pad = (c + 15) & ~15;
    incl = pad;
    int lane = t & 63;
#pragma unroll
    for (int off = 1; off < 64; off <<= 1) {
      int v = __shfl_up(incl, off, 64);
      if (lane >= off) incl += v;
    }
    if (lane == 63) wsum[t >> 6] = incl;
  }
  __syncthreads();  // uniform barrier (all 1024 threads of this block)
  if (t < 256) {
    int wv = t >> 6;
    int woff = 0;
    for (int i = 0; i < wv; ++i) woff += wsum[i];
    int excl = woff + incl - pad;
    lstart[t] = excl; lcur[t] = excl;
  }
  __syncthreads();
  for (int j = t; j < ecount; j += 1024) {
    unsigned e = ed[j];
    int p = atomicAdd(&lcur[e >> 17], 1);
    lsrc[p] = (int)(e & 0x1FFFFu);
  }
  // pad-fill: slots [start+cnt, start+padded) are disjoint from scatter
  // targets -> safe to run concurrently with the scatter loop above.
  if (t < 256) {
    int c = lcnt[t];
    int s0 = lstart[t] + c;
    int s1 = lstart[t] + ((c + 15) & ~15);
    for (int j = s0; j < s1; ++j) lsrc[j] = ZR;
  }
  __syncthreads();
  const int ebase = b * BCAP;  // BCAP % 16 == 0 -> rowstart stays 16-aligned
  int tot = wsum[0] + wsum[1] + wsum[2] + wsum[3];
  int ecountp = min(tot, BCAP);
  for (int j = 4 * t; j < ecountp; j += 4096) {  // int4 copy-out
    int4 v = *(const int4*)&lsrc[j];
    *(int4*)&eidx[ebase + j] = v;
  }
  if (t < nb) {
    rowcnt[2 * (node0 + t)]     = ebase + lstart[t];
    rowcnt[2 * (node0 + t) + 1] = lcnt[t];
  }
}

// ---------------------------------------------------------------- agg1 (fp8)
// NODE-PER-SUBGROUP: each 16-lane subgroup owns ONE node (4 nodes/wave),
// iterating its own edge list 4-at-a-time. Zero cross-lane reduction; the
// scale/f2b/store epilogue runs on all 64 lanes. 256-thread blocks
// (round-5: monolithic 1024-thread blocks strand finished waves).
__global__ __launch_bounds__(256) void k_agg1(
    const int* __restrict__ eidx, const int* __restrict__ rowcnt,
    const unsigned* __restrict__ xq, unsigned short* __restrict__ aggb, int N) {
  int wv = (blockIdx.x * 256 + threadIdx.x) >> 6;   // global wave id
  int lane = threadIdx.x & 63;
  const int sub = lane >> 4;      // which of the wave's 4 nodes
  const int li  = lane & 15;      // 8-B chunk of the 128-B fp8 row
  int n = wv * 4 + sub;
  const bool act = (n < N);
  int deg = 0;
  const int* el = eidx;
  if (act) {
    int2 rc = *(const int2*)(rowcnt + 2 * (size_t)n);
    deg = rc.y;
    el = eidx + rc.x;             // 16-int aligned (padded CSR)
  }
  f32x2 acc[4];
#pragma unroll
  for (int j = 0; j < 4; ++j) acc[j] = (f32x2){0.f, 0.f};

  for (int e = 0; e < deg; e += 4) {  // tail reads pad slots (ZR row = 0)
    int4 q = *(const int4*)(el + e);
    uint2 v0 = *(const uint2*)(xq + (size_t)q.x * 32 + li * 2);
    uint2 v1 = *(const uint2*)(xq + (size_t)q.y * 32 + li * 2);
    uint2 v2 = *(const uint2*)(xq + (size_t)q.z * 32 + li * 2);
    uint2 v3 = *(const uint2*)(xq + (size_t)q.w * 32 + li * 2);
#define ADD8(v)                                                      \
    acc[0] += __builtin_amdgcn_cvt_pk_f32_fp8(v.x, false);           \
    acc[1] += __builtin_amdgcn_cvt_pk_f32_fp8(v.x, true);            \
    acc[2] += __builtin_amdgcn_cvt_pk_f32_fp8(v.y, false);           \
    acc[3] += __builtin_amdgcn_cvt_pk_f32_fp8(v.y, true);
    ADD8(v0) ADD8(v1) ADD8(v2) ADD8(v3)
#undef ADD8
  }
  if (act) {
    float sc = 1.0f / (float)max(deg, 1);
    uint4 o4;  // lane li holds features [li*8, li*8+8): pack 8 bf16
    o4.x = (unsigned)f2b(acc[0].x * sc) | ((unsigned)f2b(acc[0].y * sc) << 16);
    o4.y = (unsigned)f2b(acc[1].x * sc) | ((unsigned)f2b(acc[1].y * sc) << 16);
    o4.z = (unsigned)f2b(acc[2].x * sc) | ((unsigned)f2b(acc[2].y * sc) << 16);
    o4.w = (unsigned)f2b(acc[3].x * sc) | ((unsigned)f2b(acc[3].y * sc) << 16);
    *(uint4*)(aggb + (size_t)n * 128 + li * 8) = o4;
  }
}

// ---------------------------------------------------------------- gemm1+2 MFMA
// h = relu([aggb | xb] @ Wb^T + b1) (K=256), then FUSED second GEMM via
// LDS round-trip (C-layout -> A-layout): Pnb = bf16(h @ Mb[0:16]^T),
// Ps = h @ Mb[16:32]^T. Mb B-frags loaded from global (8 KB, L2-hot).
__global__ __launch_bounds__(256) void k_gemm1_mfma(
    const unsigned short* __restrict__ aggb, const unsigned short* __restrict__ xb,
    const unsigned short* __restrict__ Wb, const float* __restrict__ b1,
    const unsigned short* __restrict__ Mb,
    unsigned short* __restrict__ Pnb, float* __restrict__ Ps, int N) {
  __shared__ union {
    struct { unsigned short A[128 * 40]; unsigned short W[128 * 40]; } s;
    unsigned short H[128 * 136];  // 34.8 KB h-tile, stride 136 (16B-aligned)
  } sm;
  const int t = threadIdx.x;
  const int w = t >> 6;
  const int lane = t & 63;
  const int q = lane >> 4;       // k-quad of the fragment
  const int l16 = lane & 15;
  const int row0 = blockIdx.x * 128;

  f32x4 acc[2][8];
#pragma unroll
  for (int rt = 0; rt < 2; ++rt)
#pragma unroll
    for (int ct = 0; ct < 8; ++ct) acc[rt][ct] = (f32x4){0.f, 0.f, 0.f, 0.f};

  for (int kc = 0; kc < 8; ++kc) {
    const unsigned short* Asrc = (kc < 4) ? aggb : xb;
    const int koff = (kc & 3) * 32;
#pragma unroll
    for (int i = 0; i < 2; ++i) {  // stage A: 128 rows x 32 k (8 KB)
      int idx = t + i * 256;
      int row = idx >> 2, c4 = idx & 3;
      int gr = row0 + row; if (gr >= N) gr = N - 1;
      uint4 v = *(const uint4*)(Asrc + (size_t)gr * 128 + koff + c4 * 8);
      *(uint4*)(sm.s.A + row * 40 + c4 * 8) = v;
    }
#pragma unroll
    for (int i = 0; i < 2; ++i) {  // stage W: 128 cols x 32 k (8 KB)
      int idx = t + i * 256;
      int col = idx >> 2, c4 = idx & 3;
      uint4 v = *(const uint4*)(Wb + col * 256 + kc * 32 + c4 * 8);
      *(uint4*)(sm.s.W + col * 40 + c4 * 8) = v;
    }
    __syncthreads();
    bf16x8 afr[2];
#pragma unroll
    for (int rt = 0; rt < 2; ++rt)
      afr[rt] = *(const bf16x8*)(sm.s.A + (w * 32 + rt * 16 + l16) * 40 + q * 8);
    bf16x8 bfr[8];
#pragma unroll
    for (int ct = 0; ct < 8; ++ct)
      bfr[ct] = *(const bf16x8*)(sm.s.W + (ct * 16 + l16) * 40 + q * 8);
#pragma unroll
    for (int rt = 0; rt < 2; ++rt)
#pragma unroll
      for (int ct = 0; ct < 8; ++ct)
        acc[rt][ct] = __builtin_amdgcn_mfma_f32_16x16x32_bf16(
            afr[rt], bfr[ct], acc[rt][ct], 0, 0, 0);
    __syncthreads();
  }

  // epilogue 1: bias + relu, h tile -> LDS (bf16, C-layout row = q*4+reg)
  float bv[8];
#pragma unroll
  for (int ct = 0; ct < 8; ++ct) bv[ct] = b1[ct * 16 + l16];
#pragma unroll
  for (int rt = 0; rt < 2; ++rt) {
    int rl = w * 32 + rt * 16 + q * 4;
#pragma unroll
    for (int reg = 0; reg < 4; ++reg) {
#pragma unroll
      for (int ct = 0; ct < 8; ++ct) {
        float v = acc[rt][ct][reg] + bv[ct];
        sm.H[(rl + reg) * 136 + ct * 16 + l16] = f2b(v > 0.f ? v : 0.f);
      }
    }
  }
  __syncthreads();

  // fused GEMM2: P(128x32) = h(128x128) @ Mb(32x128)^T, K=128 in 4 steps
  f32x4 acc2[2][2];
#pragma unroll
  for (int rt = 0; rt < 2; ++rt)
#pragma unroll
    for (int ct = 0; ct < 2; ++ct) acc2[rt][ct] = (f32x4){0.f, 0.f, 0.f, 0.f};
#pragma unroll
  for (int ks = 0; ks < 4; ++ks) {
    bf16x8 a2[2], b2v[2];
#pragma unroll
    for (int rt = 0; rt < 2; ++rt)
      a2[rt] = *(const bf16x8*)(sm.H + (w * 32 + rt * 16 + l16) * 136 + ks * 32 + q * 8);
#pragma unroll
    for (int ct = 0; ct < 2; ++ct)
      b2v[ct] = *(const bf16x8*)(Mb + (size_t)(ct * 16 + l16) * 128 + ks * 32 + q * 8);
#pragma unroll
    for (int rt = 0; rt < 2; ++rt)
#pragma unroll
      for (int ct = 0; ct < 2; ++ct)
        acc2[rt][ct] = __builtin_amdgcn_mfma_f32_16x16x32_bf16(
            a2[rt], b2v[ct], acc2[rt][ct], 0, 0, 0);
  }
#pragma unroll
  for (int rt = 0; rt < 2; ++rt) {
    int rbase = row0 + w * 32 + rt * 16 + q * 4;
#pragma unroll
    for (int reg = 0; reg < 4; ++reg) {
      int r = rbase + reg;
      Pnb[(size_t)r * 16 + l16] = f2b(acc2[rt][0][reg]);
      Ps[(size_t)r * 16 + l16] = acc2[rt][1][reg];
    }
  }
}

// ---------------------------------------------------------------- agg2 + out
// NODE-PER-SUBGROUP (r11 proven, −13 µs): each 4-lane subgroup owns ONE
// node (16 nodes/wave); its 4 lanes hold the node's 32-B Pnb row. Per iter:
// one broadcast int4 edge load + 4 uint2 gathers; zero cross-lane
// reduction; epilogue on all 64 lanes. Pad slots read ZR -> contribute 0.
__global__ __launch_bounds__(256) void k_agg2_out(
    const int* __restrict__ eidx, const int* __restrict__ rowcnt,
    const unsigned short* __restrict__ Pnb, const float* __restrict__ Ps,
    const float* __restrict__ bias2, float* __restrict__ out, int N) {
  int wv = (blockIdx.x * 256 + threadIdx.x) >> 6;   // global wave id
  int lane = threadIdx.x & 63;
  const int sub = lane >> 2;      // which of the wave's 16 nodes
  const int li  = lane & 3;       // 8-B chunk of the 32-B bf16 row
  int n = wv * 16 + sub;
  const bool act = (n < N);
  int deg = 0;
  const int* el = eidx;
  if (act) {
    int2 rc = *(const int2*)(rowcnt + 2 * (size_t)n);
    deg = rc.y;
    el = eidx + rc.x;             // 16-int aligned (padded CSR)
  }
  f32x2 a0 = (f32x2){0.f, 0.f}, a1 = (f32x2){0.f, 0.f};
  for (int e = 0; e < deg; e += 4) {  // tail reads pad slots (ZR row = 0)
    int4 q = *(const int4*)(el + e);  // broadcast across the sub's 4 lanes
    uint2 v0 = *(const uint2*)(Pnb + (size_t)q.x * 16 + li * 4);
    uint2 v1 = *(const uint2*)(Pnb + (size_t)q.y * 16 + li * 4);
    uint2 v2 = *(const uint2*)(Pnb + (size_t)q.z * 16 + li * 4);
    uint2 v3 = *(const uint2*)(Pnb + (size_t)q.w * 16 + li * 4);
#define ACC2(v)                                   \
    a0 += (f32x2){b2f_lo(v.x), b2f_hi(v.x)};      \
    a1 += (f32x2){b2f_lo(v.y), b2f_hi(v.y)};
    ACC2(v0) ACC2(v1) ACC2(v2) ACC2(v3)
#undef ACC2
  }
  if (act) {
    float sc = 1.0f / (float)max(deg, 1);
    float4 self = *(const float4*)(Ps + (size_t)n * 16 + li * 4);
    float4 b = *(const float4*)(bias2 + li * 4);
    float4 o;
    o.x = a0.x * sc + self.x + b.x;
    o.y = a0.y * sc + self.y + b.y;
    o.z = a1.x * sc + self.z + b.z;
    o.w = a1.y * sc + self.w + b.w;
    *(float4*)(out + (size_t)n * 16 + li * 4) = o;
  }
}

extern "C" void kernel_launch(void* const* d_in, const int* in_sizes, int n_in,
                              void* d_out, int out_size, void* d_ws, size_t ws_size,
                              hipStream_t stream) {
  const float* x   = (const float*)d_in[0];
  const int*   ei  = (const int*)d_in[1];
  const float* W1l = (const float*)d_in[2];
  const float* b1l = (const float*)d_in[3];
  const float* W1r = (const float*)d_in[4];
  const float* W2l = (const float*)d_in[5];
  const float* b2l = (const float*)d_in[6];
  const float* W2r = (const float*)d_in[7];
  const float* Wc  = (const float*)d_in[8];
  const float* bc  = (const float*)d_in[9];
  float* out = (float*)d_out;

  const int N      = in_sizes[0] / 128;
  const int E      = in_sizes[1] / 2;
  const int Np     = ((N + 127) / 128) * 128;  // pad to 128-row GEMM tiles
  const int NBUCK  = (N + 255) >> BSHIFT;
  const int ZR     = Np;                       // zero-row index (xb/xq/Pnb)
  const int NBIN   = (E + CHUNK - 1) / CHUNK;
  const int NG     = N * 32;                   // float4 groups to cast
  const int NCASTT = (NG + 1023) / 1024;       // total cast blocks
  const int NC1    = (NCASTT < CAST1) ? NCASTT : CAST1;  // in k_bin
  const int NC2    = NCASTT - NC1;                       // in k_buildcast

  char* ws = (char*)d_ws;
  size_t off = 0;
  auto alloc = [&](size_t bytes) {
    void* p = ws + off;
    off = (off + bytes + 255) & ~(size_t)255;
    return p;
  };
  int*            rowcnt   = (int*)           alloc((size_t)N * 8);
  int*            bcnt     = (int*)           alloc((size_t)MAXB * BPAD * 4);
  unsigned*       edg      = (unsigned*)      alloc((size_t)NBUCK * BCAP * 4);
  int*            eidx     = (int*)           alloc((size_t)NBUCK * BCAP * 4);
  unsigned short* xb       = (unsigned short*)alloc((size_t)(Np + 1) * 128 * 2);
  unsigned*       xq       = (unsigned*)      alloc((size_t)(Np + 1) * 32 * 4);
  unsigned short* aggb     = (unsigned short*)alloc((size_t)Np * 128 * 2);
  unsigned short* Wb       = (unsigned short*)alloc((size_t)128 * 256 * 2);
  unsigned short* Mb       = (unsigned short*)alloc((size_t)32 * 128 * 2);
  unsigned short* Pnb      = (unsigned short*)alloc((size_t)(Np + 1) * 16 * 2);
  float*          Ps       = (float*)         alloc((size_t)Np * 16 * 4);
  float*          bias2    = (float*)         alloc(16 * 4);
  (void)ws_size; (void)n_in; (void)out_size;

  hipMemsetAsync(bcnt, 0, (size_t)MAXB * BPAD * 4, stream);
  k_bin<<<NBIN + 145 + NC1, 1024, 0, stream>>>(
      ei, E, bcnt, edg,
      W1l, W1r, Wb, Wc, bc, W2l, W2r, b2l, Mb, bias2, xb, xq, Pnb, ZR, NBIN,
      x, NG);
  k_buildcast<<<NBUCK + NC2, 1024, 0, stream>>>(
      edg, bcnt, eidx, rowcnt, N, ZR, NBUCK, x, xb, xq, NG, NC1);
  k_agg1<<<(N + 15) / 16, 256, 0, stream>>>(eidx, rowcnt, xq, aggb, N);
  k_gemm1_mfma<<<Np / 128, 256, 0, stream>>>(aggb, xb, Wb, b1l, Mb, Pnb, Ps, N);
  k_agg2_out<<<(N + 63) / 64, 256, 0, stream>>>(eidx, rowcnt, Pnb, Ps, bias2, out, N);
}